// Round 1
// baseline (293.391 us; speedup 1.0000x reference)
//
#include <hip/hip_runtime.h>
#include <cstddef>
#include <cstdint>

#define F 128
#define C_OUT 10
#define SB 256   // scan block size

typedef short bf16x8 __attribute__((ext_vector_type(8)));
typedef float f32x4  __attribute__((ext_vector_type(4)));
typedef float f32x2  __attribute__((ext_vector_type(2)));
typedef unsigned u32x4 __attribute__((ext_vector_type(4)));

__device__ __forceinline__ unsigned short bf16_rne(float f) {
  unsigned u = __float_as_uint(f);
  return (unsigned short)((u + 0x7FFFu + ((u >> 16) & 1u)) >> 16);
}

// ---------------- GRU weight evolution (both layers, single-bf16 RNE) + zero counts ----
__global__ void gru_evolve2_k(const float* __restrict__ W01, const float* __restrict__ wih1,
                              const float* __restrict__ whh1, const float* __restrict__ bih1,
                              const float* __restrict__ bhh1,
                              const float* __restrict__ W02, const float* __restrict__ wih2,
                              const float* __restrict__ whh2, const float* __restrict__ bih2,
                              const float* __restrict__ bhh2,
                              unsigned short* __restrict__ Bhi1, unsigned short* __restrict__ Bhi2,
                              int* __restrict__ counts, int n) {
  if ((int)blockIdx.x >= 128) {
    int i = ((int)blockIdx.x - 128) * SB + threadIdx.x;
    if (i < n) counts[i] = 0;
    return;
  }
  int t = blockIdx.x * 256 + threadIdx.x;     // 0..32767
  int layer = t >> 14;
  int tt = t & 16383;
  const float* W0  = layer ? W02  : W01;
  const float* wih = layer ? wih2 : wih1;
  const float* whh = layer ? whh2 : whh1;
  const float* bih = layer ? bih2 : bih1;
  const float* bhh = layer ? bhh2 : bhh1;
  unsigned short* Bhi = layer ? Bhi2 : Bhi1;
  int i = tt >> 7, j = tt & 127;      // i = k (feature) index, j = w_col index
  const float4* w0r = (const float4*)(W0 + (size_t)i * F);
  float gi[3], gh[3];
#pragma unroll
  for (int g = 0; g < 3; ++g) {
    const float4* wr = (const float4*)(wih + (size_t)(g * F + j) * F);
    const float4* hr = (const float4*)(whh + (size_t)(g * F + j) * F);
    float si = 0.f, sh = 0.f;
    for (int k = 0; k < F / 4; ++k) {
      float4 a = w0r[k];
      float4 b = wr[k];
      float4 c = hr[k];
      si += a.x * b.x + a.y * b.y + a.z * b.z + a.w * b.w;
      sh += a.x * c.x + a.y * c.y + a.z * c.z + a.w * c.w;
    }
    gi[g] = si + bih[g * F + j];
    gh[g] = sh + bhh[g * F + j];
  }
  float r = 1.0f / (1.0f + expf(-(gi[0] + gh[0])));
  float z = 1.0f / (1.0f + expf(-(gi[1] + gh[1])));
  float nn = tanhf(gi[2] + r * gh[2]);
  float val = (1.0f - z) * nn + z * W0[(size_t)i * F + j];

  int kstep = i >> 5, kl = i & 31;
  int lane = (kl >> 3) * 16 + (j & 15);
  int tile = j >> 4;
  int idx = ((kstep * 8 + tile) * 64 + lane) * 8 + (kl & 7);
  Bhi[idx] = bf16_rne(val);
}

// ---------------- CSR build ----------------
__global__ void count_rank_k(const int* __restrict__ dst, int* __restrict__ counts,
                             int* __restrict__ rank, int E) {
  int e = blockIdx.x * blockDim.x + threadIdx.x;
  if (e < E) rank[e] = atomicAdd(&counts[dst[e]], 1);
}

__global__ void scan_local_k(const int* __restrict__ counts, int* __restrict__ incl,
                             int* __restrict__ blocksum, int n) {
  __shared__ int sh[SB];
  int gid = blockIdx.x * SB + threadIdx.x;
  int v = (gid < n) ? counts[gid] : 0;
  sh[threadIdx.x] = v;
  __syncthreads();
  for (int off = 1; off < SB; off <<= 1) {
    int t = 0;
    if ((int)threadIdx.x >= off) t = sh[threadIdx.x - off];
    __syncthreads();
    if ((int)threadIdx.x >= off) sh[threadIdx.x] += t;
    __syncthreads();
  }
  if (gid < n) incl[gid] = sh[threadIdx.x];
  if (threadIdx.x == SB - 1) blocksum[blockIdx.x] = sh[SB - 1];
}

__global__ void scan_finish_k(const int* __restrict__ counts, const int* __restrict__ incl,
                              const int* __restrict__ blocksum, int* __restrict__ rowptr,
                              float* __restrict__ dinv, int n, int nb) {
  __shared__ int sh[SB];
  __shared__ int orig[SB];
  int v = ((int)threadIdx.x < nb) ? blocksum[threadIdx.x] : 0;
  sh[threadIdx.x] = v;
  orig[threadIdx.x] = v;
  __syncthreads();
  for (int off = 1; off < SB; off <<= 1) {
    int t = 0;
    if ((int)threadIdx.x >= off) t = sh[threadIdx.x - off];
    __syncthreads();
    if ((int)threadIdx.x >= off) sh[threadIdx.x] += t;
    __syncthreads();
  }
  int myoff = sh[blockIdx.x] - orig[blockIdx.x];
  int gid = blockIdx.x * SB + threadIdx.x;
  if (gid >= n) return;
  int c = counts[gid];
  int inc = myoff + incl[gid];
  rowptr[gid] = inc - c;
  dinv[gid] = rsqrtf((float)c + 1.0f);
  if (gid == n - 1) rowptr[n] = inc;
}

// fill stores PRE-SHIFTED src (src<<7 = byte offset of the 128B fp8 row).
__device__ __forceinline__ void fill_body(int bid, const int* __restrict__ src,
                                          const int* __restrict__ dst,
                                          const int* __restrict__ rank,
                                          const int* __restrict__ rowptr,
                                          int* __restrict__ csr_src, int E) {
  int e = bid * 256 + (int)threadIdx.x;
  if (e < E) {
    int d = dst[e];
    csr_src[rowptr[d] + rank[e]] = src[e] << 7;
  }
}

// ---------------- MFMA GEMM: fp8 rows (128 B), single-bf16 inputs --------------------
// Transposed MFMA: D = W' (A) x X^T (B); lane owns x_row = lane&15, 4 consecutive
// w_cols per tile. Single-bf16 RNE inputs (verified: absmax unchanged vs split).
// Epilogue: fp8 e4m3 encode (HW cvt_pk_fp8_f32); row = 32 dwords = one cache line.
__device__ __forceinline__ void gemm_body(int bid, const float* __restrict__ X,
                                          const unsigned short* __restrict__ Bhi,
                                          const float* __restrict__ dinv,
                                          unsigned* __restrict__ Y, int nrows) {
  int wid = bid * 4 + ((int)threadIdx.x >> 6);
  int lane = threadIdx.x & 63;
  int ng = (nrows + 15) >> 4;
  if (wid >= ng) return;
  int g = __builtin_amdgcn_readfirstlane(wid);
  int q = lane >> 4, m = lane & 15;
  int rowA = g * 16 + m;
  if (rowA >= nrows) rowA = nrows - 1;

  f32x4 acc[8];
#pragma unroll
  for (int t = 0; t < 8; ++t) { acc[t].x = 0.f; acc[t].y = 0.f; acc[t].z = 0.f; acc[t].w = 0.f; }

#pragma unroll
  for (int s = 0; s < 4; ++s) {
    const float* xp = X + (size_t)rowA * F + s * 32 + q * 8;
    float4 xa = *(const float4*)xp;
    float4 xb = *(const float4*)(xp + 4);
    float xv[8] = {xa.x, xa.y, xa.z, xa.w, xb.x, xb.y, xb.z, xb.w};
    bf16x8 xh;
#pragma unroll
    for (int j = 0; j < 8; ++j) xh[j] = (short)bf16_rne(xv[j]);
#pragma unroll
    for (int t = 0; t < 8; ++t) {
      size_t boff = ((size_t)(s * 8 + t) * 64 + lane) * 8;
      bf16x8 wh = *(const bf16x8*)(Bhi + boff);
      acc[t] = __builtin_amdgcn_mfma_f32_16x16x32_bf16(wh, xh, acc[t], 0, 0, 0);
    }
  }

  int row = g * 16 + m;
  if (row < nrows) {
    float dd = dinv[row];
    unsigned* yr = Y + (size_t)row * 32 + q;   // lane q owns dword t*4+q
#pragma unroll
    for (int t = 0; t < 8; ++t) {
      int p = __builtin_amdgcn_cvt_pk_fp8_f32(dd * acc[t].x, dd * acc[t].y, 0, false);
      p = __builtin_amdgcn_cvt_pk_fp8_f32(dd * acc[t].z, dd * acc[t].w, p, true);
      yr[t * 4] = (unsigned)p;
    }
  }
}

__global__ void gemm_mfma_k(const float* __restrict__ X, const unsigned short* __restrict__ Bhi,
                            const float* __restrict__ dinv, unsigned* __restrict__ Y,
                            int nrows) {
  gemm_body(blockIdx.x, X, Bhi, dinv, Y, nrows);
}

// fused: blocks [0, ngemm) do layer-1 gemm; [ngemm, ...) do csr fill.
__global__ void fill_gemm_k(const float* __restrict__ X, const unsigned short* __restrict__ Bhi,
                            const float* __restrict__ dinv, unsigned* __restrict__ Y,
                            int nrows, int ngemm,
                            const int* __restrict__ src, const int* __restrict__ dst,
                            const int* __restrict__ rank, const int* __restrict__ rowptr,
                            int* __restrict__ csr_src, int E) {
  if ((int)blockIdx.x < ngemm)
    gemm_body(blockIdx.x, X, Bhi, dinv, Y, nrows);
  else
    fill_body((int)blockIdx.x - ngemm, src, dst, rank, rowptr, csr_src, E);
}

// ---------------- gather aggregation (wide-gather form): fp8 rows (128 B) ------------
// One wave per node. lane = g*8 + j: g = edge slot (8 edges in parallel),
// j = 16-byte feature chunk (features j*16 .. j*16+15). Each lane gathers one
// dwordx4 (16 B) of a row: 4x fewer gather instrs and 4x the bytes-in-flight of
// the old per-dword form. Edge indices come from one per-lane broadcast load
// csr_src[i+g] per 8 edges (no cndmask select chains). csr entries are
// PRE-SHIFTED byte offsets (row<<7). Decode via HW cvt_pk_f32_fp8 into two
// accumulator banks; fold the 8 edge slots with a 3-level shfl_xor butterfly.
template <bool FUSE_LOGITS>
__global__ void agg_fp8_k(const int* __restrict__ rowptr, const int* __restrict__ csr_src,
                          const float* __restrict__ dinv, const unsigned* __restrict__ xwp,
                          float* __restrict__ hout,
                          const float* __restrict__ lw, const float* __restrict__ lb,
                          float* __restrict__ outp, int n) {
  int wave = (int)((blockIdx.x * blockDim.x + threadIdx.x) >> 6);
  int lane = threadIdx.x & 63;
  if (wave >= n) return;
  int node = __builtin_amdgcn_readfirstlane(wave);
  int g = lane >> 3, j = lane & 7;
  unsigned j16 = (unsigned)(j << 4);
  float dd = dinv[node];
  const char* __restrict__ cb = (const char*)xwp;   // row = 128 bytes

  f32x2 acc[8], bcc[8];
#pragma unroll
  for (int k = 0; k < 8; ++k) {
    acc[k].x = 0.f; acc[k].y = 0.f;
    bcc[k].x = 0.f; bcc[k].y = 0.f;
  }

#define DEC4(U, A)                                                   \
  do {                                                               \
    A[0] += __builtin_amdgcn_cvt_pk_f32_fp8((int)(U)[0], false);     \
    A[1] += __builtin_amdgcn_cvt_pk_f32_fp8((int)(U)[0], true);      \
    A[2] += __builtin_amdgcn_cvt_pk_f32_fp8((int)(U)[1], false);     \
    A[3] += __builtin_amdgcn_cvt_pk_f32_fp8((int)(U)[1], true);      \
    A[4] += __builtin_amdgcn_cvt_pk_f32_fp8((int)(U)[2], false);     \
    A[5] += __builtin_amdgcn_cvt_pk_f32_fp8((int)(U)[2], true);      \
    A[6] += __builtin_amdgcn_cvt_pk_f32_fp8((int)(U)[3], false);     \
    A[7] += __builtin_amdgcn_cvt_pk_f32_fp8((int)(U)[3], true);      \
  } while (0)

  // self-loop: g==0 lanes contribute the node's own row (others zeroed)
  {
    u32x4 u = *(const u32x4*)(cb + ((((unsigned)node) << 7) | j16));
    if (g) { u[0] = 0u; u[1] = 0u; u[2] = 0u; u[3] = 0u; }
    DEC4(u, bcc);
  }

  int b = rowptr[node], e = rowptr[node + 1];
  int i = b;
  // 32-edge main loop: 4 dwordx4 gathers (64 B) in flight per lane
  for (; i + 32 <= e; i += 32) {
    int t0 = csr_src[i + g];
    int t1 = csr_src[i + 8 + g];
    int t2 = csr_src[i + 16 + g];
    int t3 = csr_src[i + 24 + g];
    u32x4 u0 = *(const u32x4*)(cb + (((unsigned)t0) | j16));
    u32x4 u1 = *(const u32x4*)(cb + (((unsigned)t1) | j16));
    u32x4 u2 = *(const u32x4*)(cb + (((unsigned)t2) | j16));
    u32x4 u3 = *(const u32x4*)(cb + (((unsigned)t3) | j16));
    DEC4(u0, acc);
    DEC4(u1, bcc);
    DEC4(u2, acc);
    DEC4(u3, bcc);
  }
  // 16-edge step (the common case for mean degree 16)
  for (; i + 16 <= e; i += 16) {
    int t0 = csr_src[i + g];
    int t1 = csr_src[i + 8 + g];
    u32x4 u0 = *(const u32x4*)(cb + (((unsigned)t0) | j16));
    u32x4 u1 = *(const u32x4*)(cb + (((unsigned)t1) | j16));
    DEC4(u0, acc);
    DEC4(u1, bcc);
  }
  if (i + 8 <= e) {
    int t0 = csr_src[i + g];
    u32x4 u0 = *(const u32x4*)(cb + (((unsigned)t0) | j16));
    DEC4(u0, acc);
    i += 8;
  }
  if (i < e) {
    // may read csr_src up to 7 ints past e (stays inside workspace); clamp the
    // dependent gather address BEFORE loading so poison never forms an address.
    int t = csr_src[i + g];
    bool valid = (i + g) < e;
    unsigned addr = valid ? (((unsigned)t) | j16) : j16;   // row 0 as safe dummy
    u32x4 u = *(const u32x4*)(cb + addr);
    if (!valid) { u[0] = 0u; u[1] = 0u; u[2] = 0u; u[3] = 0u; }
    DEC4(u, bcc);
  }
#undef DEC4

#pragma unroll
  for (int k = 0; k < 8; ++k) { acc[k].x += bcc[k].x; acc[k].y += bcc[k].y; }

  // fold the 8 edge slots (lane bits 3,4,5); every lane ends with the full sum
  // for its 16-feature chunk
#pragma unroll
  for (int k = 0; k < 8; ++k) {
    acc[k].x += __shfl_xor(acc[k].x, 8);
    acc[k].y += __shfl_xor(acc[k].y, 8);
    acc[k].x += __shfl_xor(acc[k].x, 16);
    acc[k].y += __shfl_xor(acc[k].y, 16);
    acc[k].x += __shfl_xor(acc[k].x, 32);
    acc[k].y += __shfl_xor(acc[k].y, 32);
  }

  float hv[16];
#pragma unroll
  for (int k = 0; k < 8; ++k) {
    hv[2 * k]     = fmaxf(dd * acc[k].x, 0.f);
    hv[2 * k + 1] = fmaxf(dd * acc[k].y, 0.f);
  }

  if (!FUSE_LOGITS) {
    if (g == 0) {
      float4* hp = (float4*)(hout + (size_t)node * F + j * 16);
      hp[0] = make_float4(hv[0], hv[1], hv[2], hv[3]);
      hp[1] = make_float4(hv[4], hv[5], hv[6], hv[7]);
      hp[2] = make_float4(hv[8], hv[9], hv[10], hv[11]);
      hp[3] = make_float4(hv[12], hv[13], hv[14], hv[15]);
    }
  } else {
    // classes distributed over edge-slot groups: group g owns class g, and
    // groups 0,1 additionally own classes 8,9. j-lanes hold feature chunks;
    // butterfly over j (bits 0,1,2) completes each dot product.
    const float* w1 = lw + (size_t)g * F + j * 16;
    float v1 = 0.f;
#pragma unroll
    for (int q = 0; q < 4; ++q) {
      float4 w = *(const float4*)(w1 + q * 4);
      v1 += hv[4 * q] * w.x + hv[4 * q + 1] * w.y + hv[4 * q + 2] * w.z + hv[4 * q + 3] * w.w;
    }
    float v2 = 0.f;
    if (g < 2) {
      const float* w2 = lw + (size_t)(8 + g) * F + j * 16;
#pragma unroll
      for (int q = 0; q < 4; ++q) {
        float4 w = *(const float4*)(w2 + q * 4);
        v2 += hv[4 * q] * w.x + hv[4 * q + 1] * w.y + hv[4 * q + 2] * w.z + hv[4 * q + 3] * w.w;
      }
    }
    v1 += __shfl_xor(v1, 1); v1 += __shfl_xor(v1, 2); v1 += __shfl_xor(v1, 4);
    v2 += __shfl_xor(v2, 1); v2 += __shfl_xor(v2, 2); v2 += __shfl_xor(v2, 4);
    v1 += lb[g];
    if (g < 2) v2 += lb[8 + g];
    // global max over the 10 classes (v2 only valid for g<2)
    float m = (g < 2) ? fmaxf(v1, v2) : v1;
    m = fmaxf(m, __shfl_xor(m, 8));
    m = fmaxf(m, __shfl_xor(m, 16));
    m = fmaxf(m, __shfl_xor(m, 32));
    float ex = expf(v1 - m) + ((g < 2) ? expf(v2 - m) : 0.f);
    ex += __shfl_xor(ex, 8); ex += __shfl_xor(ex, 16); ex += __shfl_xor(ex, 32);
    float lse = m + logf(ex);
    if (j == 0) {
      outp[(size_t)node * C_OUT + g] = v1 - lse;
      if (g < 2) outp[(size_t)node * C_OUT + 8 + g] = v2 - lse;
    }
  }
}

extern "C" void kernel_launch(void* const* d_in, const int* in_sizes, int n_in,
                              void* d_out, int out_size, void* d_ws, size_t ws_size,
                              hipStream_t stream) {
  const float* x    = (const float*)d_in[0];
  const int*   ei   = (const int*)d_in[1];
  const float* W1   = (const float*)d_in[2];
  const float* wih1 = (const float*)d_in[3];
  const float* whh1 = (const float*)d_in[4];
  const float* bih1 = (const float*)d_in[5];
  const float* bhh1 = (const float*)d_in[6];
  const float* W2   = (const float*)d_in[7];
  const float* wih2 = (const float*)d_in[8];
  const float* whh2 = (const float*)d_in[9];
  const float* bih2 = (const float*)d_in[10];
  const float* bhh2 = (const float*)d_in[11];
  const float* lw   = (const float*)d_in[12];
  const float* lb   = (const float*)d_in[13];
  float* out = (float*)d_out;

  int N = in_sizes[0] / F;
  int E = in_sizes[1] / 2;
  const int* src = ei;
  const int* dst = ei + E;
  int nb = (N + SB - 1) / SB;   // 196 (must be <= 256)
  int ng = (N + 15) / 16;
  int ngemm = (ng + 3) / 4;
  int nfill = (E + 255) / 256;
  int nagg = (N + 3) / 4;

  float* ws = (float*)d_ws;
  unsigned* bufA = (unsigned*)ws;                // N*32 dwords (fp8 rows, 128 B)
  float* bufB = (float*)(bufA + (size_t)N * 32); // N*F floats (h)
  float* dinv = bufB + (size_t)N * F;            // N
  unsigned short* Bhi1 = (unsigned short*)(dinv + N);  // 16384
  unsigned short* Bhi2 = Bhi1 + F * F;                 // 16384
  int* counts = (int*)(Bhi2 + F * F);            // N
  int* rowptr = counts + N;                      // N+1
  int* rank   = rowptr + N + 1;                  // E
  int* incl   = rank + E;                        // N
  int* blocksum = incl + N;                      // 256
  int* csr_src = blocksum + 256;                 // E

  gru_evolve2_k<<<128 + nb, 256, 0, stream>>>(W1, wih1, whh1, bih1, bhh1,
                                              W2, wih2, whh2, bih2, bhh2,
                                              Bhi1, Bhi2, counts, N);

  count_rank_k<<<(E + 255) / 256, 256, 0, stream>>>(dst, counts, rank, E);
  scan_local_k<<<nb, SB, 0, stream>>>(counts, incl, blocksum, N);
  scan_finish_k<<<nb, SB, 0, stream>>>(counts, incl, blocksum, rowptr, dinv, N, nb);

  // layer 1 gemm + csr fill (independent; fused dispatch)
  fill_gemm_k<<<ngemm + nfill, 256, 0, stream>>>(x, Bhi1, dinv, bufA, N, ngemm,
                                                 src, dst, rank, rowptr, csr_src, E);
  agg_fp8_k<false><<<nagg, 256, 0, stream>>>(rowptr, csr_src, dinv, bufA, bufB,
                                             nullptr, nullptr, nullptr, N);

  // layer 2 (logits fused)
  gemm_mfma_k<<<ngemm, 256, 0, stream>>>(bufB, Bhi2, dinv, bufA, N);
  agg_fp8_k<true><<<nagg, 256, 0, stream>>>(rowptr, csr_src, dinv, bufA, nullptr,
                                            lw, lb, out, N);
}

// Round 2
// 262.493 us; speedup vs baseline: 1.1177x; 1.1177x over previous
//
#include <hip/hip_runtime.h>
#include <cstddef>
#include <cstdint>

#define F 128
#define C_OUT 10
#define SB 256   // scan block size

typedef short bf16x8 __attribute__((ext_vector_type(8)));
typedef float f32x4  __attribute__((ext_vector_type(4)));
typedef float f32x2  __attribute__((ext_vector_type(2)));

__device__ __forceinline__ unsigned short bf16_rne(float f) {
  unsigned u = __float_as_uint(f);
  return (unsigned short)((u + 0x7FFFu + ((u >> 16) & 1u)) >> 16);
}

// ---------------- GRU weight evolution (both layers, single-bf16 RNE) + zero counts ----
__global__ void gru_evolve2_k(const float* __restrict__ W01, const float* __restrict__ wih1,
                              const float* __restrict__ whh1, const float* __restrict__ bih1,
                              const float* __restrict__ bhh1,
                              const float* __restrict__ W02, const float* __restrict__ wih2,
                              const float* __restrict__ whh2, const float* __restrict__ bih2,
                              const float* __restrict__ bhh2,
                              unsigned short* __restrict__ Bhi1, unsigned short* __restrict__ Bhi2,
                              int* __restrict__ counts, int n) {
  if ((int)blockIdx.x >= 128) {
    int i = ((int)blockIdx.x - 128) * SB + threadIdx.x;
    if (i < n) counts[i] = 0;
    return;
  }
  int t = blockIdx.x * 256 + threadIdx.x;     // 0..32767
  int layer = t >> 14;
  int tt = t & 16383;
  const float* W0  = layer ? W02  : W01;
  const float* wih = layer ? wih2 : wih1;
  const float* whh = layer ? whh2 : whh1;
  const float* bih = layer ? bih2 : bih1;
  const float* bhh = layer ? bhh2 : bhh1;
  unsigned short* Bhi = layer ? Bhi2 : Bhi1;
  int i = tt >> 7, j = tt & 127;      // i = k (feature) index, j = w_col index
  const float4* w0r = (const float4*)(W0 + (size_t)i * F);
  float gi[3], gh[3];
#pragma unroll
  for (int g = 0; g < 3; ++g) {
    const float4* wr = (const float4*)(wih + (size_t)(g * F + j) * F);
    const float4* hr = (const float4*)(whh + (size_t)(g * F + j) * F);
    float si = 0.f, sh = 0.f;
    for (int k = 0; k < F / 4; ++k) {
      float4 a = w0r[k];
      float4 b = wr[k];
      float4 c = hr[k];
      si += a.x * b.x + a.y * b.y + a.z * b.z + a.w * b.w;
      sh += a.x * c.x + a.y * c.y + a.z * c.z + a.w * c.w;
    }
    gi[g] = si + bih[g * F + j];
    gh[g] = sh + bhh[g * F + j];
  }
  float r = 1.0f / (1.0f + expf(-(gi[0] + gh[0])));
  float z = 1.0f / (1.0f + expf(-(gi[1] + gh[1])));
  float nn = tanhf(gi[2] + r * gh[2]);
  float val = (1.0f - z) * nn + z * W0[(size_t)i * F + j];

  int kstep = i >> 5, kl = i & 31;
  int lane = (kl >> 3) * 16 + (j & 15);
  int tile = j >> 4;
  int idx = ((kstep * 8 + tile) * 64 + lane) * 8 + (kl & 7);
  Bhi[idx] = bf16_rne(val);
}

// ---------------- CSR build ----------------
__global__ void count_rank_k(const int* __restrict__ dst, int* __restrict__ counts,
                             int* __restrict__ rank, int E) {
  int e = blockIdx.x * blockDim.x + threadIdx.x;
  if (e < E) rank[e] = atomicAdd(&counts[dst[e]], 1);
}

__global__ void scan_local_k(const int* __restrict__ counts, int* __restrict__ incl,
                             int* __restrict__ blocksum, int n) {
  __shared__ int sh[SB];
  int gid = blockIdx.x * SB + threadIdx.x;
  int v = (gid < n) ? counts[gid] : 0;
  sh[threadIdx.x] = v;
  __syncthreads();
  for (int off = 1; off < SB; off <<= 1) {
    int t = 0;
    if ((int)threadIdx.x >= off) t = sh[threadIdx.x - off];
    __syncthreads();
    if ((int)threadIdx.x >= off) sh[threadIdx.x] += t;
    __syncthreads();
  }
  if (gid < n) incl[gid] = sh[threadIdx.x];
  if (threadIdx.x == SB - 1) blocksum[blockIdx.x] = sh[SB - 1];
}

__global__ void scan_finish_k(const int* __restrict__ counts, const int* __restrict__ incl,
                              const int* __restrict__ blocksum, int* __restrict__ rowptr,
                              float* __restrict__ dinv, int n, int nb) {
  __shared__ int sh[SB];
  __shared__ int orig[SB];
  int v = ((int)threadIdx.x < nb) ? blocksum[threadIdx.x] : 0;
  sh[threadIdx.x] = v;
  orig[threadIdx.x] = v;
  __syncthreads();
  for (int off = 1; off < SB; off <<= 1) {
    int t = 0;
    if ((int)threadIdx.x >= off) t = sh[threadIdx.x - off];
    __syncthreads();
    if ((int)threadIdx.x >= off) sh[threadIdx.x] += t;
    __syncthreads();
  }
  int myoff = sh[blockIdx.x] - orig[blockIdx.x];
  int gid = blockIdx.x * SB + threadIdx.x;
  if (gid >= n) return;
  int c = counts[gid];
  int inc = myoff + incl[gid];
  rowptr[gid] = inc - c;
  dinv[gid] = rsqrtf((float)c + 1.0f);
  if (gid == n - 1) rowptr[n] = inc;
}

// fill stores PRE-SHIFTED src (src<<7 = byte offset of the 128B fp8 row).
__device__ __forceinline__ void fill_body(int bid, const int* __restrict__ src,
                                          const int* __restrict__ dst,
                                          const int* __restrict__ rank,
                                          const int* __restrict__ rowptr,
                                          int* __restrict__ csr_src, int E) {
  int e = bid * 256 + (int)threadIdx.x;
  if (e < E) {
    int d = dst[e];
    csr_src[rowptr[d] + rank[e]] = src[e] << 7;
  }
}

// ---------------- MFMA GEMM: fp8 rows (128 B), single-bf16 inputs --------------------
// Transposed MFMA: D = W' (A) x X^T (B); lane owns x_row = lane&15, 4 consecutive
// w_cols per tile. Single-bf16 RNE inputs (verified: absmax unchanged vs split).
// Epilogue: fp8 e4m3 encode (HW cvt_pk_fp8_f32); row = 32 dwords = one cache line.
__device__ __forceinline__ void gemm_body(int bid, const float* __restrict__ X,
                                          const unsigned short* __restrict__ Bhi,
                                          const float* __restrict__ dinv,
                                          unsigned* __restrict__ Y, int nrows) {
  int wid = bid * 4 + ((int)threadIdx.x >> 6);
  int lane = threadIdx.x & 63;
  int ng = (nrows + 15) >> 4;
  if (wid >= ng) return;
  int g = __builtin_amdgcn_readfirstlane(wid);
  int q = lane >> 4, m = lane & 15;
  int rowA = g * 16 + m;
  if (rowA >= nrows) rowA = nrows - 1;

  f32x4 acc[8];
#pragma unroll
  for (int t = 0; t < 8; ++t) { acc[t].x = 0.f; acc[t].y = 0.f; acc[t].z = 0.f; acc[t].w = 0.f; }

#pragma unroll
  for (int s = 0; s < 4; ++s) {
    const float* xp = X + (size_t)rowA * F + s * 32 + q * 8;
    float4 xa = *(const float4*)xp;
    float4 xb = *(const float4*)(xp + 4);
    float xv[8] = {xa.x, xa.y, xa.z, xa.w, xb.x, xb.y, xb.z, xb.w};
    bf16x8 xh;
#pragma unroll
    for (int j = 0; j < 8; ++j) xh[j] = (short)bf16_rne(xv[j]);
#pragma unroll
    for (int t = 0; t < 8; ++t) {
      size_t boff = ((size_t)(s * 8 + t) * 64 + lane) * 8;
      bf16x8 wh = *(const bf16x8*)(Bhi + boff);
      acc[t] = __builtin_amdgcn_mfma_f32_16x16x32_bf16(wh, xh, acc[t], 0, 0, 0);
    }
  }

  int row = g * 16 + m;
  if (row < nrows) {
    float dd = dinv[row];
    unsigned* yr = Y + (size_t)row * 32 + q;   // lane q owns dword t*4+q
#pragma unroll
    for (int t = 0; t < 8; ++t) {
      int p = __builtin_amdgcn_cvt_pk_fp8_f32(dd * acc[t].x, dd * acc[t].y, 0, false);
      p = __builtin_amdgcn_cvt_pk_fp8_f32(dd * acc[t].z, dd * acc[t].w, p, true);
      yr[t * 4] = (unsigned)p;
    }
  }
}

__global__ void gemm_mfma_k(const float* __restrict__ X, const unsigned short* __restrict__ Bhi,
                            const float* __restrict__ dinv, unsigned* __restrict__ Y,
                            int nrows) {
  gemm_body(blockIdx.x, X, Bhi, dinv, Y, nrows);
}

// fused: blocks [0, ngemm) do layer-1 gemm; [ngemm, ...) do csr fill.
__global__ void fill_gemm_k(const float* __restrict__ X, const unsigned short* __restrict__ Bhi,
                            const float* __restrict__ dinv, unsigned* __restrict__ Y,
                            int nrows, int ngemm,
                            const int* __restrict__ src, const int* __restrict__ dst,
                            const int* __restrict__ rank, const int* __restrict__ rowptr,
                            int* __restrict__ csr_src, int E) {
  if ((int)blockIdx.x < ngemm)
    gemm_body(blockIdx.x, X, Bhi, dinv, Y, nrows);
  else
    fill_body((int)blockIdx.x - ngemm, src, dst, rank, rowptr, csr_src, E);
}

// ---------------- gather aggregation: fp8 rows (128 B), half-wave, per-lane csr -----
// One wave per node. Lanes 0-31 even edges, 32-63 odd edges; lane (half,hm) loads
// one dword = 4 fp8 cols {4hm..4hm+3} (half-wave covers a full 128B row => each
// gather instruction touches exactly 2 cache lines). csr entries PRE-SHIFTED byte
// offsets (row<<7). KEY CHANGE vs R0: each lane loads its OWN edge offset via the
// per-lane base cp = csr_src + half, so cp[i+2k] IS edge i+2k+half. This removes
// all 16 uniform csr loads + 16 cndmask/or selects per 16-edge iteration while
// keeping the same 8-gather + 8-csr-load memory-level parallelism (the R1 lesson:
// MLP and 2-lines-per-gather matter more than raw instruction count).
template <bool FUSE_LOGITS>
__global__ void agg_fp8_k(const int* __restrict__ rowptr, const int* __restrict__ csr_src,
                          const float* __restrict__ dinv, const unsigned* __restrict__ xwp,
                          float* __restrict__ hout,
                          const float* __restrict__ lw, const float* __restrict__ lb,
                          float* __restrict__ outp, int n) {
  int wave = (int)((blockIdx.x * blockDim.x + threadIdx.x) >> 6);
  int lane = threadIdx.x & 63;
  if (wave >= n) return;
  int node = __builtin_amdgcn_readfirstlane(wave);
  int half = lane >> 5, hm = lane & 31;
  float dd = dinv[node];
  const char* __restrict__ cb = (const char*)xwp;   // row = 128 bytes
  unsigned loff = (unsigned)(hm << 2);
  f32x2 acc0 = {0.f, 0.f}, acc1 = {0.f, 0.f};
  f32x2 bcc0 = {0.f, 0.f}, bcc1 = {0.f, 0.f};

#define DEC(U, A, B)                                           \
  do {                                                         \
    (A) += __builtin_amdgcn_cvt_pk_f32_fp8((int)(U), false);   \
    (B) += __builtin_amdgcn_cvt_pk_f32_fp8((int)(U), true);    \
  } while (0)

  // self-loop (lower half only; upper half contributes 0)
  {
    unsigned u = *(const unsigned*)(cb + ((((unsigned)node) << 7) | loff));
    if (half) u = 0u;
    DEC(u, acc0, acc1);
  }

  int b = rowptr[node], e = rowptr[node + 1];
  const int* __restrict__ cp = csr_src + half;   // per-lane: cp[i+2k] = edge i+2k+half
  int i = b;
  // 16-edge main loop: 8 per-lane csr loads + 8 gathers in flight per wave
  for (; i + 16 <= e; i += 16) {
    int s0 = cp[i + 0],  s1 = cp[i + 2],  s2 = cp[i + 4],  s3 = cp[i + 6];
    int s4 = cp[i + 8],  s5 = cp[i + 10], s6 = cp[i + 12], s7 = cp[i + 14];
    unsigned u0 = *(const unsigned*)(cb + (((unsigned)s0) | loff));
    unsigned u1 = *(const unsigned*)(cb + (((unsigned)s1) | loff));
    unsigned u2 = *(const unsigned*)(cb + (((unsigned)s2) | loff));
    unsigned u3 = *(const unsigned*)(cb + (((unsigned)s3) | loff));
    unsigned u4 = *(const unsigned*)(cb + (((unsigned)s4) | loff));
    unsigned u5 = *(const unsigned*)(cb + (((unsigned)s5) | loff));
    unsigned u6 = *(const unsigned*)(cb + (((unsigned)s6) | loff));
    unsigned u7 = *(const unsigned*)(cb + (((unsigned)s7) | loff));
    DEC(u0, acc0, acc1);
    DEC(u1, bcc0, bcc1);
    DEC(u2, acc0, acc1);
    DEC(u3, bcc0, bcc1);
    DEC(u4, acc0, acc1);
    DEC(u5, bcc0, bcc1);
    DEC(u6, acc0, acc1);
    DEC(u7, bcc0, bcc1);
  }
  // 8-edge tail
  if (i + 8 <= e) {
    int s0 = cp[i + 0], s1 = cp[i + 2], s2 = cp[i + 4], s3 = cp[i + 6];
    unsigned u0 = *(const unsigned*)(cb + (((unsigned)s0) | loff));
    unsigned u1 = *(const unsigned*)(cb + (((unsigned)s1) | loff));
    unsigned u2 = *(const unsigned*)(cb + (((unsigned)s2) | loff));
    unsigned u3 = *(const unsigned*)(cb + (((unsigned)s3) | loff));
    DEC(u0, acc0, acc1);
    DEC(u1, bcc0, bcc1);
    DEC(u2, acc0, acc1);
    DEC(u3, bcc0, bcc1);
    i += 8;
  }
  // 4-edge tail
  if (i + 4 <= e) {
    int s0 = cp[i + 0], s1 = cp[i + 2];
    unsigned u0 = *(const unsigned*)(cb + (((unsigned)s0) | loff));
    unsigned u1 = *(const unsigned*)(cb + (((unsigned)s1) | loff));
    DEC(u0, acc0, acc1);
    DEC(u1, bcc0, bcc1);
    i += 4;
  }
  // 2-edge tail
  if (i + 2 <= e) {
    int s0 = cp[i];
    unsigned u = *(const unsigned*)(cb + (((unsigned)s0) | loff));
    DEC(u, acc0, acc1);
    i += 2;
  }
  // single remaining edge: half 0 processes it; half 1 clamps the csr index
  // (so no read past e) and zeroes its contribution.
  if (i < e) {
    int idx = i + half;
    if (idx >= e) idx = e - 1;
    int s = csr_src[idx];
    unsigned u = *(const unsigned*)(cb + (((unsigned)s) | loff));
    if (half) u = 0u;
    DEC(u, bcc0, bcc1);
  }
#undef DEC
  acc0 += bcc0;
  acc1 += bcc1;

  // combine the two halves (both end up with the full sum)
  acc0.x += __shfl_xor(acc0.x, 32);
  acc0.y += __shfl_xor(acc0.y, 32);
  acc1.x += __shfl_xor(acc1.x, 32);
  acc1.y += __shfl_xor(acc1.y, 32);

  float h0 = fmaxf(dd * acc0.x, 0.f);
  float h1 = fmaxf(dd * acc0.y, 0.f);
  float h2 = fmaxf(dd * acc1.x, 0.f);
  float h3 = fmaxf(dd * acc1.y, 0.f);

  if (!FUSE_LOGITS) {
    if (half == 0) {
      *(float4*)(hout + (size_t)node * F + hm * 4) = make_float4(h0, h1, h2, h3);
    }
  } else {
    float acc[C_OUT];
#pragma unroll
    for (int c = 0; c < C_OUT; ++c) {
      float4 w = *(const float4*)(lw + (size_t)c * F + hm * 4);
      float v = h0 * w.x + h1 * w.y + h2 * w.z + h3 * w.w;
      v += __shfl_xor(v, 1); v += __shfl_xor(v, 2);
      v += __shfl_xor(v, 4); v += __shfl_xor(v, 8);
      v += __shfl_xor(v, 16);
      acc[c] = v + lb[c];
    }
    float mx = acc[0];
#pragma unroll
    for (int c = 1; c < C_OUT; ++c) mx = fmaxf(mx, acc[c]);
    float s = 0.f;
#pragma unroll
    for (int c = 0; c < C_OUT; ++c) s += expf(acc[c] - mx);
    float lse = mx + logf(s);
#pragma unroll
    for (int c = 0; c < C_OUT; ++c)
      if (lane == c) outp[(size_t)node * C_OUT + c] = acc[c] - lse;
  }
}

extern "C" void kernel_launch(void* const* d_in, const int* in_sizes, int n_in,
                              void* d_out, int out_size, void* d_ws, size_t ws_size,
                              hipStream_t stream) {
  const float* x    = (const float*)d_in[0];
  const int*   ei   = (const int*)d_in[1];
  const float* W1   = (const float*)d_in[2];
  const float* wih1 = (const float*)d_in[3];
  const float* whh1 = (const float*)d_in[4];
  const float* bih1 = (const float*)d_in[5];
  const float* bhh1 = (const float*)d_in[6];
  const float* W2   = (const float*)d_in[7];
  const float* wih2 = (const float*)d_in[8];
  const float* whh2 = (const float*)d_in[9];
  const float* bih2 = (const float*)d_in[10];
  const float* bhh2 = (const float*)d_in[11];
  const float* lw   = (const float*)d_in[12];
  const float* lb   = (const float*)d_in[13];
  float* out = (float*)d_out;

  int N = in_sizes[0] / F;
  int E = in_sizes[1] / 2;
  const int* src = ei;
  const int* dst = ei + E;
  int nb = (N + SB - 1) / SB;   // 196 (must be <= 256)
  int ng = (N + 15) / 16;
  int ngemm = (ng + 3) / 4;
  int nfill = (E + 255) / 256;
  int nagg = (N + 3) / 4;

  float* ws = (float*)d_ws;
  unsigned* bufA = (unsigned*)ws;                // N*32 dwords (fp8 rows, 128 B)
  float* bufB = (float*)(bufA + (size_t)N * 32); // N*F floats (h)
  float* dinv = bufB + (size_t)N * F;            // N
  unsigned short* Bhi1 = (unsigned short*)(dinv + N);  // 16384
  unsigned short* Bhi2 = Bhi1 + F * F;                 // 16384
  int* counts = (int*)(Bhi2 + F * F);            // N
  int* rowptr = counts + N;                      // N+1
  int* rank   = rowptr + N + 1;                  // E
  int* incl   = rank + E;                        // N
  int* blocksum = incl + N;                      // 256
  int* csr_src = blocksum + 256;                 // E

  gru_evolve2_k<<<128 + nb, 256, 0, stream>>>(W1, wih1, whh1, bih1, bhh1,
                                              W2, wih2, whh2, bih2, bhh2,
                                              Bhi1, Bhi2, counts, N);

  count_rank_k<<<(E + 255) / 256, 256, 0, stream>>>(dst, counts, rank, E);
  scan_local_k<<<nb, SB, 0, stream>>>(counts, incl, blocksum, N);
  scan_finish_k<<<nb, SB, 0, stream>>>(counts, incl, blocksum, rowptr, dinv, N, nb);

  // layer 1 gemm + csr fill (independent; fused dispatch)
  fill_gemm_k<<<ngemm + nfill, 256, 0, stream>>>(x, Bhi1, dinv, bufA, N, ngemm,
                                                 src, dst, rank, rowptr, csr_src, E);
  agg_fp8_k<false><<<nagg, 256, 0, stream>>>(rowptr, csr_src, dinv, bufA, bufB,
                                             nullptr, nullptr, nullptr, N);

  // layer 2 (logits fused)
  gemm_mfma_k<<<ngemm, 256, 0, stream>>>(bufB, Bhi2, dinv, bufA, N);
  agg_fp8_k<true><<<nagg, 256, 0, stream>>>(rowptr, csr_src, dinv, bufA, nullptr,
                                            lw, lb, out, N);
}